// Round 3
// baseline (16255.620 us; speedup 1.0000x reference)
//
#include <hip/hip_runtime.h>
#include <cstdint>
#include <cstddef>

typedef unsigned short u16;
typedef short bf16x8 __attribute__((ext_vector_type(8)));
typedef float f32x4 __attribute__((ext_vector_type(4)));
typedef unsigned short u16x4 __attribute__((ext_vector_type(4)));

#define T_LEN 1200

// workspace byte offsets (all 256-aligned). Total ~47.9 MB.
#define O_X     0ull           // x bf16: 38400*512*2        = 39,321,600
#define O_WIH   39321600ull    // W_ih cat bf16: 4096*512*2  =  4,194,304
#define O_WHH   43515904ull    // W_hh cat bf16: 4096*512*2  =  4,194,304
#define O_BIAS  47710208ull    // bias cat f32: 4096*4       =     16,384
#define O_HBUF  47726592ull    // h dbl-buf bf16: 2*2*32*512*2 =   131,072
#define O_FLG   47857664ull    // 64 flags x 64B             =      4,096
#define WS_NEED 47861760ull

#define HO 19660800ull   // h_n offset in d_out (floats)
#define CO 19693568ull   // c_n offset in d_out (floats)

__device__ __forceinline__ u16 f2bf(float f) {
  union { float f; unsigned u; } v; v.f = f;
  unsigned r = v.u + 0x7FFFu + ((v.u >> 16) & 1u);
  return (u16)(r >> 16);
}
__device__ __forceinline__ float sigm(float x) { return 1.f / (1.f + __expf(-x)); }
__device__ __forceinline__ float tanh_s(float x) {
  float ax = fabsf(x);
  float e = __expf(-2.f * ax);          // in (0,1], no overflow
  float t = (1.f - e) / (1.f + e);
  return x < 0.f ? -t : t;
}

// ---------------- cast x (f32 -> bf16), 4 elems/thread ----------------
__global__ __launch_bounds__(256) void cast_x_k(const float4* __restrict__ x,
                                                u16* __restrict__ xb) {
  int i = blockIdx.x * 256 + threadIdx.x;   // 4,915,200 threads
  float4 v = x[i];
  u16x4 o;
  o.x = f2bf(v.x); o.y = f2bf(v.y); o.z = f2bf(v.z); o.w = f2bf(v.w);
  *(u16x4*)(xb + (size_t)i * 4) = o;
}

// ---------------- concat + cast weights, fold biases ----------------
__global__ __launch_bounds__(256) void prep_w_k(
    const float* __restrict__ wih_f, const float* __restrict__ whh_f,
    const float* __restrict__ bih_f, const float* __restrict__ bhh_f,
    const float* __restrict__ wih_b, const float* __restrict__ whh_b,
    const float* __restrict__ bih_b, const float* __restrict__ bhh_b,
    u16* __restrict__ Wih, u16* __restrict__ Whh, float* __restrict__ bias) {
  int tid = blockIdx.x * 256 + threadIdx.x;   // 0 .. 4096*512-1
  int g = tid >> 9;
  float vi, vh;
  if (g < 2048) { vi = wih_f[tid]; vh = whh_f[tid]; }
  else { int t2 = tid - (2048 * 512); vi = wih_b[t2]; vh = whh_b[t2]; }
  Wih[tid] = f2bf(vi);
  Whh[tid] = f2bf(vh);
  if ((tid & 511) == 0) {
    bias[g] = (g < 2048) ? (bih_f[g] + bhh_f[g]) : (bih_b[g - 2048] + bhh_b[g - 2048]);
  }
}

// ---------------- persistent bidirectional LSTM recurrence ----------------
// 64 blocks: dir = bx>>5, slice = bx&31 (16 h-cols each). W_ih/W_hh slices
// live in registers (AGPR-eligible) as MFMA B-fragments for all 1200 steps.
// Sync: per-block epoch flags (64B-padded, no RMW): writer publishes
// flag=t+1 with RELEASE store after its h(t+1) slice is drained; readers
// gather the 32 flags of their direction with relaxed agent loads and
// acquire-fence once satisfied. Double-buffered h: flag>=t implies everyone
// finished reading h(t-1), so slot (t+1)&1 is safe to overwrite.
__global__ __launch_bounds__(256, 1) void lstm_rec(const u16* __restrict__ X,
                                                   const u16* __restrict__ Wih,
                                                   const u16* __restrict__ Whh,
                                                   const float* __restrict__ bias,
                                                   const int* __restrict__ lengths,
                                                   u16* __restrict__ hbuf,
                                                   float* __restrict__ out,
                                                   unsigned* __restrict__ flags) {
  const int tid = threadIdx.x, lane = tid & 63, wid = tid >> 6;
  const int bx = blockIdx.x;
  const int dir = bx >> 5, slice = bx & 31, c0 = slice * 16;
  const int quad = lane >> 4, l15 = lane & 15;

  __shared__ float h_m[32][16];
  __shared__ float c_m[32][16];
  __shared__ float pre[4][32][16];
  __shared__ int len_s[32];

  if (tid < 32) len_s[tid] = lengths[tid];
  h_m[tid >> 4][tid & 15] = 0.f;          c_m[tid >> 4][tid & 15] = 0.f;
  h_m[(tid + 256) >> 4][tid & 15] = 0.f;  c_m[(tid + 256) >> 4][tid & 15] = 0.f;

  // B-fragments (resident whole loop): wave `wid` owns gate `wid` (i/f/g/o),
  // 16 gate cols. B[k][n] layout: n = l15, k = ks*32 + quad*8 + j.
  bf16x8 bh[16], bxw[16];
  {
    const size_t wrow = (size_t)(dir * 2048 + wid * 512 + c0 + l15) * 512 + quad * 8;
#pragma unroll
    for (int ks = 0; ks < 16; ++ks) {
      bh[ks]  = *(const bf16x8*)(Whh + wrow + (size_t)ks * 32);
      bxw[ks] = *(const bf16x8*)(Wih + wrow + (size_t)ks * 32);
    }
  }
  __syncthreads();

  const int b0 = tid >> 4, colv = tid & 15, b1 = b0 + 16;
  const int hcol = c0 + colv;
  const float bi  = bias[dir * 2048 + 0 * 512 + hcol];
  const float bfv = bias[dir * 2048 + 1 * 512 + hcol];
  const float bg  = bias[dir * 2048 + 2 * 512 + hcol];
  const float bo  = bias[dir * 2048 + 3 * 512 + hcol];

  unsigned* myflag = flags + (size_t)bx * 16;
  const unsigned* pollflag = flags + (size_t)(dir * 32 + (lane & 31)) * 16;

  for (int t = 0; t < T_LEN; ++t) {
    const u16* hb = hbuf + (size_t)((t & 1) * 32768 + dir * 16384);
    u16* hbw      = hbuf + (size_t)(((t + 1) & 1) * 32768 + dir * 16384);

    // ---- x loads first: h-independent, latency hides under the flag poll ----
    const int ba = l15, bb = 16 + l15;
    int lena = len_s[ba], lenb = len_s[bb];
    int tta = (dir == 0) ? t : (lena - 1 - t);  if (tta < 0) tta = 0;
    int ttb = (dir == 0) ? t : (lenb - 1 - t);  if (ttb < 0) ttb = 0;
    const u16* xrow0 = X + ((size_t)tta * 32 + ba) * 512 + quad * 8;
    const u16* xrow1 = X + ((size_t)ttb * 32 + bb) * 512 + quad * 8;
    bf16x8 ax0[16], ax1[16];
#pragma unroll
    for (int ks = 0; ks < 16; ++ks) {
      ax0[ks] = *(const bf16x8*)(xrow0 + (size_t)ks * 32);
      ax1[ks] = *(const bf16x8*)(xrow1 + (size_t)ks * 32);
    }

    // ---- wait: all blocks of my direction have published h(t) ----
    if (wid == 0) {
      for (;;) {
        unsigned v = __hip_atomic_load(pollflag, __ATOMIC_RELAXED, __HIP_MEMORY_SCOPE_AGENT);
        if (__all((int)(v >= (unsigned)t))) break;
        __builtin_amdgcn_s_sleep(2);
      }
    }
    __syncthreads();
    __builtin_amdgcn_fence(__ATOMIC_ACQUIRE, "agent");  // inv L1/L2 before h reads

    // ---- gate GEMM: [x_t, h] . [W_ih; W_hh]^T, two m-tiles ----
    const u16* hrow0 = hb + (size_t)ba * 512 + quad * 8;
    const u16* hrow1 = hb + (size_t)bb * 512 + quad * 8;
    f32x4 acc0 = {0.f, 0.f, 0.f, 0.f}, acc1 = {0.f, 0.f, 0.f, 0.f};
#pragma unroll
    for (int ks = 0; ks < 16; ++ks) {
      bf16x8 ah0 = *(const bf16x8*)(hrow0 + (size_t)ks * 32);
      bf16x8 ah1 = *(const bf16x8*)(hrow1 + (size_t)ks * 32);
      acc0 = __builtin_amdgcn_mfma_f32_16x16x32_bf16(ax0[ks], bxw[ks], acc0, 0, 0, 0);
      acc1 = __builtin_amdgcn_mfma_f32_16x16x32_bf16(ax1[ks], bxw[ks], acc1, 0, 0, 0);
      acc0 = __builtin_amdgcn_mfma_f32_16x16x32_bf16(ah0, bh[ks], acc0, 0, 0, 0);
      acc1 = __builtin_amdgcn_mfma_f32_16x16x32_bf16(ah1, bh[ks], acc1, 0, 0, 0);
    }
    // C/D layout: row (=batch in tile) = quad*4+r, col (=gate col) = l15
#pragma unroll
    for (int r = 0; r < 4; ++r) {
      pre[wid][quad * 4 + r][l15]      = acc0[r];
      pre[wid][16 + quad * 4 + r][l15] = acc1[r];
    }
    __syncthreads();

    // ---- cell update + h(t+1) publish (out atomics deferred past publish) ----
    int len0 = len_s[b0], len1 = len_s[b1];
    int tt0 = (dir == 0) ? t : (len0 - 1 - t);
    int tt1 = (dir == 0) ? t : (len1 - 1 - t);
    bool m0 = (dir == 0) ? (t < len0) : (tt0 >= 0);
    bool m1 = (dir == 0) ? (t < len1) : (tt1 >= 0);
    if (tt0 < 0) tt0 = 0;
    if (tt1 < 0) tt1 = 0;

    float hn0 = 0.f, hn1 = 0.f;
    {
      float hold = h_m[b0][colv];
      if (m0) {
        float gi = pre[0][b0][colv] + bi,  gf = pre[1][b0][colv] + bfv;
        float gg = pre[2][b0][colv] + bg,  go = pre[3][b0][colv] + bo;
        float cn = sigm(gf) * c_m[b0][colv] + sigm(gi) * tanh_s(gg);
        hn0 = sigm(go) * tanh_s(cn);
        c_m[b0][colv] = cn; h_m[b0][colv] = hn0; hold = hn0;
      }
      hbw[(size_t)b0 * 512 + hcol] = f2bf(hold);
    }
    {
      float hold = h_m[b1][colv];
      if (m1) {
        float gi = pre[0][b1][colv] + bi,  gf = pre[1][b1][colv] + bfv;
        float gg = pre[2][b1][colv] + bg,  go = pre[3][b1][colv] + bo;
        float cn = sigm(gf) * c_m[b1][colv] + sigm(gi) * tanh_s(gg);
        hn1 = sigm(go) * tanh_s(cn);
        c_m[b1][colv] = cn; h_m[b1][colv] = hn1; hold = hn1;
      }
      hbw[(size_t)b1 * 512 + hcol] = f2bf(hold);
    }

    __syncthreads();   // drains this block's h stores to L2 (vmcnt0 before barrier)
    if (tid == 0)      // RELEASE: wbL2 flushes the whole XCD L2 (all waves' h lines)
      __hip_atomic_store(myflag, (unsigned)(t + 1), __ATOMIC_RELEASE, __HIP_MEMORY_SCOPE_AGENT);

    // out accumulation off the critical path (device-scope atomics, next
    // iteration's syncthreads drains them while others poll)
    if (m0) atomicAdd(out + (size_t)(tt0 * 32 + b0) * 512 + hcol, hn0);
    if (m1) atomicAdd(out + (size_t)(tt1 * 32 + b1) * 512 + hcol, hn1);
  }

  // finals: h_n (2,B,H), c_n (2,B,H)
  out[HO + (size_t)dir * 16384 + (size_t)b0 * 512 + hcol] = h_m[b0][colv];
  out[HO + (size_t)dir * 16384 + (size_t)b1 * 512 + hcol] = h_m[b1][colv];
  out[CO + (size_t)dir * 16384 + (size_t)b0 * 512 + hcol] = c_m[b0][colv];
  out[CO + (size_t)dir * 16384 + (size_t)b1 * 512 + hcol] = c_m[b1][colv];
}

extern "C" void kernel_launch(void* const* d_in, const int* in_sizes, int n_in,
                              void* d_out, int out_size, void* d_ws, size_t ws_size,
                              hipStream_t stream) {
  const float* x     = (const float*)d_in[0];
  const int*   lens  = (const int*)d_in[1];
  const float* wih_f = (const float*)d_in[2];
  const float* whh_f = (const float*)d_in[3];
  const float* bih_f = (const float*)d_in[4];
  const float* bhh_f = (const float*)d_in[5];
  const float* wih_b = (const float*)d_in[6];
  const float* whh_b = (const float*)d_in[7];
  const float* bih_b = (const float*)d_in[8];
  const float* bhh_b = (const float*)d_in[9];
  float* out = (float*)d_out;
  char* ws = (char*)d_ws;

  u16*      xb   = (u16*)(ws + O_X);
  u16*      Wih  = (u16*)(ws + O_WIH);
  u16*      Whh  = (u16*)(ws + O_WHH);
  float*    bias = (float*)(ws + O_BIAS);
  u16*      hbuf = (u16*)(ws + O_HBUF);
  unsigned* flg  = (unsigned*)(ws + O_FLG);

  hipMemsetAsync(hbuf, 0, 131072 + 4096, stream);               // h dbl-buf + flags
  hipMemsetAsync(d_out, 0, (size_t)out_size * 4, stream);       // out accumulated via atomics

  cast_x_k<<<19200, 256, 0, stream>>>((const float4*)x, xb);
  prep_w_k<<<8192, 256, 0, stream>>>(wih_f, whh_f, bih_f, bhh_f,
                                     wih_b, whh_b, bih_b, bhh_b, Wih, Whh, bias);
  lstm_rec<<<64, 256, 0, stream>>>(xb, Wih, Whh, bias, lens, hbuf, out, flg);
}

// Round 5
// 15018.959 us; speedup vs baseline: 1.0823x; 1.0823x over previous
//
#include <hip/hip_runtime.h>
#include <cstdint>
#include <cstddef>

typedef unsigned short u16;
typedef unsigned long long u64;
typedef short bf16x8 __attribute__((ext_vector_type(8)));
typedef float f32x4 __attribute__((ext_vector_type(4)));
typedef unsigned short u16x4 __attribute__((ext_vector_type(4)));

#define T_LEN 1200

// workspace byte offsets (all 256-aligned). Total ~47.9 MB.
#define O_X     0ull           // x bf16: 38400*512*2        = 39,321,600
#define O_WIH   39321600ull    // W_ih cat bf16: 4096*512*2  =  4,194,304
#define O_WHH   43515904ull    // W_hh cat bf16: 4096*512*2  =  4,194,304
#define O_BIAS  47710208ull    // bias cat f32: 4096*4       =     16,384
#define O_HBUF  47726592ull    // h dbl-buf bf16: 2*2*32*512*2 =   131,072
#define O_FLG   47857664ull    // 64 flags x 64B             =      4,096
#define WS_NEED 47861760ull

#define HO 19660800ull   // h_n offset in d_out (floats)
#define CO 19693568ull   // c_n offset in d_out (floats)

__device__ __forceinline__ u16 f2bf(float f) {
  union { float f; unsigned u; } v; v.f = f;
  unsigned r = v.u + 0x7FFFu + ((v.u >> 16) & 1u);
  return (u16)(r >> 16);
}
__device__ __forceinline__ float sigm(float x) { return 1.f / (1.f + __expf(-x)); }
__device__ __forceinline__ float tanh_s(float x) {
  float ax = fabsf(x);
  float e = __expf(-2.f * ax);          // in (0,1], no overflow
  float t = (1.f - e) / (1.f + e);
  return x < 0.f ? -t : t;
}

// device-coherent 8B load / 4B store via compiler-supported relaxed scoped
// atomics: emit global_load/store with sc0 sc1 (LLC-direct), NO wbL2/invL2.
__device__ __forceinline__ u64 ld_dev64(const u16* p) {
  return __hip_atomic_load((const u64*)p, __ATOMIC_RELAXED, __HIP_MEMORY_SCOPE_AGENT);
}
__device__ __forceinline__ void st_dev32(u16* p, unsigned v) {
  __hip_atomic_store((unsigned*)p, v, __ATOMIC_RELAXED, __HIP_MEMORY_SCOPE_AGENT);
}

// ---------------- cast x (f32 -> bf16), 4 elems/thread ----------------
__global__ __launch_bounds__(256) void cast_x_k(const float4* __restrict__ x,
                                                u16* __restrict__ xb) {
  int i = blockIdx.x * 256 + threadIdx.x;   // 4,915,200 threads
  float4 v = x[i];
  u16x4 o;
  o.x = f2bf(v.x); o.y = f2bf(v.y); o.z = f2bf(v.z); o.w = f2bf(v.w);
  *(u16x4*)(xb + (size_t)i * 4) = o;
}

// ---------------- concat + cast weights, fold biases ----------------
__global__ __launch_bounds__(256) void prep_w_k(
    const float* __restrict__ wih_f, const float* __restrict__ whh_f,
    const float* __restrict__ bih_f, const float* __restrict__ bhh_f,
    const float* __restrict__ wih_b, const float* __restrict__ whh_b,
    const float* __restrict__ bih_b, const float* __restrict__ bhh_b,
    u16* __restrict__ Wih, u16* __restrict__ Whh, float* __restrict__ bias) {
  int tid = blockIdx.x * 256 + threadIdx.x;   // 0 .. 4096*512-1
  int g = tid >> 9;
  float vi, vh;
  if (g < 2048) { vi = wih_f[tid]; vh = whh_f[tid]; }
  else { int t2 = tid - (2048 * 512); vi = wih_b[t2]; vh = whh_b[t2]; }
  Wih[tid] = f2bf(vi);
  Whh[tid] = f2bf(vh);
  if ((tid & 511) == 0) {
    bias[g] = (g < 2048) ? (bih_f[g] + bhh_f[g]) : (bih_b[g - 2048] + bhh_b[g - 2048]);
  }
}

// ---------------- persistent bidirectional LSTM recurrence ----------------
// 64 blocks: dir = bx>>5, slice = bx&31 (16 h-cols each). W_ih/W_hh slices
// live in registers as MFMA B-fragments for all 1200 steps.
//
// Sync protocol — ZERO cache-maintenance instructions (R2/R3's 13.4us/step
// was attributed to per-step wbL2+invL2 from release/acquire):
//   h and flags are accessed ONLY with relaxed agent-scope atomics
//   (sc0 sc1 -> memory-side LLC, coherent across XCDs by construction).
//   Producer: cell -> shfl-pack -> 4B atomic h stores -> __syncthreads
//   (emits s_waitcnt vmcnt(0): stores acked at LLC) -> relaxed flag store.
//   Consumer: relaxed flag poll -> __syncthreads -> 8B atomic h loads.
//   x/weights stay plain-cached; with no invalidates they stay L2-resident.
__global__ __launch_bounds__(256, 1) void lstm_rec(const u16* __restrict__ X,
                                                   const u16* __restrict__ Wih,
                                                   const u16* __restrict__ Whh,
                                                   const float* __restrict__ bias,
                                                   const int* __restrict__ lengths,
                                                   u16* __restrict__ hbuf,
                                                   float* __restrict__ out,
                                                   unsigned* __restrict__ flags) {
  const int tid = threadIdx.x, lane = tid & 63, wid = tid >> 6;
  const int bx = blockIdx.x;
  const int dir = bx >> 5, slice = bx & 31, c0 = slice * 16;
  const int quad = lane >> 4, l15 = lane & 15;

  __shared__ float h_m[32][16];
  __shared__ float c_m[32][16];
  __shared__ float pre[4][32][16];
  __shared__ int len_s[32];

  if (tid < 32) len_s[tid] = lengths[tid];
  h_m[tid >> 4][tid & 15] = 0.f;          c_m[tid >> 4][tid & 15] = 0.f;
  h_m[(tid + 256) >> 4][tid & 15] = 0.f;  c_m[(tid + 256) >> 4][tid & 15] = 0.f;

  // B-fragments (resident whole loop): wave `wid` owns gate `wid` (i/f/g/o),
  // 16 gate cols. B[k][n] layout: n = l15, k = ks*32 + quad*8 + j.
  bf16x8 bh[16], bxw[16];
  {
    const size_t wrow = (size_t)(dir * 2048 + wid * 512 + c0 + l15) * 512 + quad * 8;
#pragma unroll
    for (int ks = 0; ks < 16; ++ks) {
      bh[ks]  = *(const bf16x8*)(Whh + wrow + (size_t)ks * 32);
      bxw[ks] = *(const bf16x8*)(Wih + wrow + (size_t)ks * 32);
    }
  }
  __syncthreads();

  const int b0 = tid >> 4, colv = tid & 15, b1 = b0 + 16;
  const int hcol = c0 + colv;
  const float bi  = bias[dir * 2048 + 0 * 512 + hcol];
  const float bfv = bias[dir * 2048 + 1 * 512 + hcol];
  const float bg  = bias[dir * 2048 + 2 * 512 + hcol];
  const float bo  = bias[dir * 2048 + 3 * 512 + hcol];

  unsigned* myflag = flags + (size_t)bx * 16;
  const unsigned* pollflag = flags + (size_t)(dir * 32 + (lane & 31)) * 16;

  for (int t = 0; t < T_LEN; ++t) {
    const u16* hb = hbuf + (size_t)((t & 1) * 32768 + dir * 16384);
    u16* hbw      = hbuf + (size_t)(((t + 1) & 1) * 32768 + dir * 16384);

    // ---- x loads first: h-independent, L2-cached, hide under the poll ----
    const int ba = l15, bb = 16 + l15;
    int lena = len_s[ba], lenb = len_s[bb];
    int tta = (dir == 0) ? t : (lena - 1 - t);  if (tta < 0) tta = 0;
    int ttb = (dir == 0) ? t : (lenb - 1 - t);  if (ttb < 0) ttb = 0;
    const u16* xrow0 = X + ((size_t)tta * 32 + ba) * 512 + quad * 8;
    const u16* xrow1 = X + ((size_t)ttb * 32 + bb) * 512 + quad * 8;
    bf16x8 ax0[16], ax1[16];
#pragma unroll
    for (int ks = 0; ks < 16; ++ks) {
      ax0[ks] = *(const bf16x8*)(xrow0 + (size_t)ks * 32);
      ax1[ks] = *(const bf16x8*)(xrow1 + (size_t)ks * 32);
    }

    // ---- wait: all blocks of my direction have published h(t) ----
    if (wid == 0) {
      for (;;) {
        unsigned v = __hip_atomic_load(pollflag, __ATOMIC_RELAXED, __HIP_MEMORY_SCOPE_AGENT);
        if (__all((int)(v >= (unsigned)t))) break;
        __builtin_amdgcn_s_sleep(1);
      }
    }
    __syncthreads();
    asm volatile("" ::: "memory");   // compiler-only barrier: no h-load hoisting

    // ---- issue h loads (LLC-direct 8B atomics), overlap with x-part MFMA ----
    const u16* hrow0 = hb + (size_t)ba * 512 + quad * 8;
    const u16* hrow1 = hb + (size_t)bb * 512 + quad * 8;
    union Uq { u64 q[2]; bf16x8 v; };
    Uq ah0[16], ah1[16];
#pragma unroll
    for (int ks = 0; ks < 16; ++ks) {
      ah0[ks].q[0] = ld_dev64(hrow0 + (size_t)ks * 32);
      ah0[ks].q[1] = ld_dev64(hrow0 + (size_t)ks * 32 + 4);
      ah1[ks].q[0] = ld_dev64(hrow1 + (size_t)ks * 32);
      ah1[ks].q[1] = ld_dev64(hrow1 + (size_t)ks * 32 + 4);
    }

    // x-part MFMAs run while h loads are in flight (no dependence)
    f32x4 a0x = {0.f,0.f,0.f,0.f}, a1x = {0.f,0.f,0.f,0.f};
#pragma unroll
    for (int ks = 0; ks < 16; ++ks) {
      a0x = __builtin_amdgcn_mfma_f32_16x16x32_bf16(ax0[ks], bxw[ks], a0x, 0, 0, 0);
      a1x = __builtin_amdgcn_mfma_f32_16x16x32_bf16(ax1[ks], bxw[ks], a1x, 0, 0, 0);
    }
    f32x4 a0h = {0.f,0.f,0.f,0.f}, a1h = {0.f,0.f,0.f,0.f};
#pragma unroll
    for (int ks = 0; ks < 16; ++ks) {
      a0h = __builtin_amdgcn_mfma_f32_16x16x32_bf16(ah0[ks].v, bh[ks], a0h, 0, 0, 0);
      a1h = __builtin_amdgcn_mfma_f32_16x16x32_bf16(ah1[ks].v, bh[ks], a1h, 0, 0, 0);
    }
    f32x4 acc0 = a0x + a0h, acc1 = a1x + a1h;
    // C/D layout: row (=batch in tile) = quad*4+r, col (=gate col) = l15
#pragma unroll
    for (int r = 0; r < 4; ++r) {
      pre[wid][quad * 4 + r][l15]      = acc0[r];
      pre[wid][16 + quad * 4 + r][l15] = acc1[r];
    }
    __syncthreads();

    // ---- cell update ----
    int len0 = len_s[b0], len1 = len_s[b1];
    int tt0 = (dir == 0) ? t : (len0 - 1 - t);
    int tt1 = (dir == 0) ? t : (len1 - 1 - t);
    bool m0 = (dir == 0) ? (t < len0) : (tt0 >= 0);
    bool m1 = (dir == 0) ? (t < len1) : (tt1 >= 0);
    if (tt0 < 0) tt0 = 0;
    if (tt1 < 0) tt1 = 0;

    float hold0 = h_m[b0][colv], hold1 = h_m[b1][colv];
    float hn0 = 0.f, hn1 = 0.f;
    if (m0) {
      float gi = pre[0][b0][colv] + bi,  gf = pre[1][b0][colv] + bfv;
      float gg = pre[2][b0][colv] + bg,  go = pre[3][b0][colv] + bo;
      float cn = sigm(gf) * c_m[b0][colv] + sigm(gi) * tanh_s(gg);
      hn0 = sigm(go) * tanh_s(cn);
      c_m[b0][colv] = cn; h_m[b0][colv] = hn0; hold0 = hn0;
    }
    if (m1) {
      float gi = pre[0][b1][colv] + bi,  gf = pre[1][b1][colv] + bfv;
      float gg = pre[2][b1][colv] + bg,  go = pre[3][b1][colv] + bo;
      float cn = sigm(gf) * c_m[b1][colv] + sigm(gi) * tanh_s(gg);
      hn1 = sigm(go) * tanh_s(cn);
      c_m[b1][colv] = cn; h_m[b1][colv] = hn1; hold1 = hn1;
    }

    // ---- h(t+1) publish: shfl-pack pairs -> 4B LLC-direct stores ----
    unsigned p0 = (unsigned)f2bf(hold0), p1 = (unsigned)f2bf(hold1);
    unsigned q0 = (unsigned)__shfl_xor((int)p0, 1);
    unsigned q1 = (unsigned)__shfl_xor((int)p1, 1);
    if ((colv & 1) == 0) {
      st_dev32(hbw + (size_t)b0 * 512 + hcol, p0 | (q0 << 16));
      st_dev32(hbw + (size_t)b1 * 512 + hcol, p1 | (q1 << 16));
    }
    asm volatile("" ::: "memory");
    __syncthreads();   // vmcnt(0) drain: every wave's h stores acked at LLC
    if (tid == 0)
      __hip_atomic_store(myflag, (unsigned)(t + 1), __ATOMIC_RELAXED, __HIP_MEMORY_SCOPE_AGENT);

    // out accumulation fully off the critical path
    if (m0) atomicAdd(out + (size_t)(tt0 * 32 + b0) * 512 + hcol, hn0);
    if (m1) atomicAdd(out + (size_t)(tt1 * 32 + b1) * 512 + hcol, hn1);
  }

  // finals: h_n (2,B,H), c_n (2,B,H)
  out[HO + (size_t)dir * 16384 + (size_t)b0 * 512 + hcol] = h_m[b0][colv];
  out[HO + (size_t)dir * 16384 + (size_t)b1 * 512 + hcol] = h_m[b1][colv];
  out[CO + (size_t)dir * 16384 + (size_t)b0 * 512 + hcol] = c_m[b0][colv];
  out[CO + (size_t)dir * 16384 + (size_t)b1 * 512 + hcol] = c_m[b1][colv];
}

extern "C" void kernel_launch(void* const* d_in, const int* in_sizes, int n_in,
                              void* d_out, int out_size, void* d_ws, size_t ws_size,
                              hipStream_t stream) {
  const float* x     = (const float*)d_in[0];
  const int*   lens  = (const int*)d_in[1];
  const float* wih_f = (const float*)d_in[2];
  const float* whh_f = (const float*)d_in[3];
  const float* bih_f = (const float*)d_in[4];
  const float* bhh_f = (const float*)d_in[5];
  const float* wih_b = (const float*)d_in[6];
  const float* whh_b = (const float*)d_in[7];
  const float* bih_b = (const float*)d_in[8];
  const float* bhh_b = (const float*)d_in[9];
  float* out = (float*)d_out;
  char* ws = (char*)d_ws;

  u16*      xb   = (u16*)(ws + O_X);
  u16*      Wih  = (u16*)(ws + O_WIH);
  u16*      Whh  = (u16*)(ws + O_WHH);
  float*    bias = (float*)(ws + O_BIAS);
  u16*      hbuf = (u16*)(ws + O_HBUF);
  unsigned* flg  = (unsigned*)(ws + O_FLG);

  hipMemsetAsync(hbuf, 0, 131072 + 4096, stream);               // h dbl-buf + flags
  hipMemsetAsync(d_out, 0, (size_t)out_size * 4, stream);       // out accumulated via atomics

  cast_x_k<<<19200, 256, 0, stream>>>((const float4*)x, xb);
  prep_w_k<<<8192, 256, 0, stream>>>(wih_f, whh_f, bih_f, bhh_f,
                                     wih_b, whh_b, bih_b, bhh_b, Wih, Whh, bias);
  lstm_rec<<<64, 256, 0, stream>>>(xb, Wih, Whh, bias, lens, hbuf, out, flg);
}

// Round 6
// 10962.592 us; speedup vs baseline: 1.4828x; 1.3700x over previous
//
#include <hip/hip_runtime.h>
#include <cstdint>
#include <cstddef>

typedef unsigned short u16;
typedef unsigned long long u64;
typedef short bf16x8 __attribute__((ext_vector_type(8)));
typedef float f32x4 __attribute__((ext_vector_type(4)));
typedef unsigned short u16x4 __attribute__((ext_vector_type(4)));

#define T_LEN 1200

// workspace byte offsets (all 256-aligned). Total ~47.9 MB.
#define O_X     0ull           // x bf16: 38400*512*2        = 39,321,600
#define O_WIH   39321600ull    // W_ih cat bf16: 4096*512*2  =  4,194,304
#define O_WHH   43515904ull    // W_hh cat bf16: 4096*512*2  =  4,194,304
#define O_BIAS  47710208ull    // bias cat f32: 4096*4       =     16,384
#define O_HBUF  47726592ull    // h dbl-buf bf16: 2*2*32*512*2 =   131,072
#define O_FLG   47857664ull    // 64 flags x 64B             =      4,096
#define WS_NEED 47861760ull

#define HO 19660800ull   // h_n offset in d_out (floats)
#define CO 19693568ull   // c_n offset in d_out (floats)

#define HROW 516         // padded LDS row stride (u16 elems): +4 pad -> 2-way banks (free)

__device__ __forceinline__ u16 f2bf(float f) {
  union { float f; unsigned u; } v; v.f = f;
  unsigned r = v.u + 0x7FFFu + ((v.u >> 16) & 1u);
  return (u16)(r >> 16);
}
__device__ __forceinline__ float sigm(float x) { return 1.f / (1.f + __expf(-x)); }
__device__ __forceinline__ float tanh_s(float x) {
  float ax = fabsf(x);
  float e = __expf(-2.f * ax);          // in (0,1], no overflow
  float t = (1.f - e) / (1.f + e);
  return x < 0.f ? -t : t;
}

// device-coherent 8B load / 4B store via compiler-supported relaxed scoped
// atomics: emit global_load/store with sc0 sc1 (LLC-direct), NO wbL2/invL2.
__device__ __forceinline__ u64 ld_dev64(const u16* p) {
  return __hip_atomic_load((const u64*)p, __ATOMIC_RELAXED, __HIP_MEMORY_SCOPE_AGENT);
}
__device__ __forceinline__ void st_dev32(u16* p, unsigned v) {
  __hip_atomic_store((unsigned*)p, v, __ATOMIC_RELAXED, __HIP_MEMORY_SCOPE_AGENT);
}

// ---------------- cast x (f32 -> bf16), 4 elems/thread ----------------
__global__ __launch_bounds__(256) void cast_x_k(const float4* __restrict__ x,
                                                u16* __restrict__ xb) {
  int i = blockIdx.x * 256 + threadIdx.x;   // 4,915,200 threads
  float4 v = x[i];
  u16x4 o;
  o.x = f2bf(v.x); o.y = f2bf(v.y); o.z = f2bf(v.z); o.w = f2bf(v.w);
  *(u16x4*)(xb + (size_t)i * 4) = o;
}

// ---------------- concat + cast weights, fold biases ----------------
__global__ __launch_bounds__(256) void prep_w_k(
    const float* __restrict__ wih_f, const float* __restrict__ whh_f,
    const float* __restrict__ bih_f, const float* __restrict__ bhh_f,
    const float* __restrict__ wih_b, const float* __restrict__ whh_b,
    const float* __restrict__ bih_b, const float* __restrict__ bhh_b,
    u16* __restrict__ Wih, u16* __restrict__ Whh, float* __restrict__ bias) {
  int tid = blockIdx.x * 256 + threadIdx.x;   // 0 .. 4096*512-1
  int g = tid >> 9;
  float vi, vh;
  if (g < 2048) { vi = wih_f[tid]; vh = whh_f[tid]; }
  else { int t2 = tid - (2048 * 512); vi = wih_b[t2]; vh = whh_b[t2]; }
  Wih[tid] = f2bf(vi);
  Whh[tid] = f2bf(vh);
  if ((tid & 511) == 0) {
    bias[g] = (g < 2048) ? (bih_f[g] + bhh_f[g]) : (bih_b[g - 2048] + bhh_b[g - 2048]);
  }
}

// ---------------- persistent bidirectional LSTM recurrence ----------------
// 64 blocks: dir = bx>>5, slice = bx&31 (16 h-cols each). W_ih/W_hh slices
// live in registers as MFMA B-fragments for all 1200 steps.
//
// R6 change: h(t) is staged into LDS ONCE per block with COALESCED 8B
// LLC-direct loads (lane-consecutive addresses), instead of each of the 4
// waves issuing its own 1KB-strided scattered fragment loads (4x traffic,
// 64 scattered fabric transactions per instruction — the suspected
// 12.5us/step cost). Waves then read A-fragments via ds_read_b128 from a
// +4-elem padded LDS image. x-part MFMAs issue between the staging loads
// and their LDS writes to hide the LLC round trip.
__global__ __launch_bounds__(256, 1) void lstm_rec(const u16* __restrict__ X,
                                                   const u16* __restrict__ Wih,
                                                   const u16* __restrict__ Whh,
                                                   const float* __restrict__ bias,
                                                   const int* __restrict__ lengths,
                                                   u16* __restrict__ hbuf,
                                                   float* __restrict__ out,
                                                   unsigned* __restrict__ flags) {
  const int tid = threadIdx.x, lane = tid & 63, wid = tid >> 6;
  const int bx = blockIdx.x;
  const int dir = bx >> 5, slice = bx & 31, c0 = slice * 16;
  const int quad = lane >> 4, l15 = lane & 15;

  __shared__ alignas(16) u16 h_l[32 * HROW];   // staged h(t), padded rows
  __shared__ float h_m[32][16];
  __shared__ float c_m[32][16];
  __shared__ float pre[4][32][16];
  __shared__ int len_s[32];

  if (tid < 32) len_s[tid] = lengths[tid];
  h_m[tid >> 4][tid & 15] = 0.f;          c_m[tid >> 4][tid & 15] = 0.f;
  h_m[(tid + 256) >> 4][tid & 15] = 0.f;  c_m[(tid + 256) >> 4][tid & 15] = 0.f;

  // B-fragments (resident whole loop): wave `wid` owns gate `wid` (i/f/g/o),
  // 16 gate cols. B[k][n] layout: n = l15, k = ks*32 + quad*8 + j.
  bf16x8 bh[16], bxw[16];
  {
    const size_t wrow = (size_t)(dir * 2048 + wid * 512 + c0 + l15) * 512 + quad * 8;
#pragma unroll
    for (int ks = 0; ks < 16; ++ks) {
      bh[ks]  = *(const bf16x8*)(Whh + wrow + (size_t)ks * 32);
      bxw[ks] = *(const bf16x8*)(Wih + wrow + (size_t)ks * 32);
    }
  }
  __syncthreads();

  const int b0 = tid >> 4, colv = tid & 15, b1 = b0 + 16;
  const int hcol = c0 + colv;
  const float bi  = bias[dir * 2048 + 0 * 512 + hcol];
  const float bfv = bias[dir * 2048 + 1 * 512 + hcol];
  const float bg  = bias[dir * 2048 + 2 * 512 + hcol];
  const float bo  = bias[dir * 2048 + 3 * 512 + hcol];

  unsigned* myflag = flags + (size_t)bx * 16;
  const unsigned* pollflag = flags + (size_t)(dir * 32 + (lane & 31)) * 16;

  for (int t = 0; t < T_LEN; ++t) {
    const u16* hb = hbuf + (size_t)((t & 1) * 32768 + dir * 16384);
    u16* hbw      = hbuf + (size_t)(((t + 1) & 1) * 32768 + dir * 16384);

    // ---- x loads first: h-independent, L2-cached, hide under the poll ----
    const int ba = l15, bb = 16 + l15;
    int lena = len_s[ba], lenb = len_s[bb];
    int tta = (dir == 0) ? t : (lena - 1 - t);  if (tta < 0) tta = 0;
    int ttb = (dir == 0) ? t : (lenb - 1 - t);  if (ttb < 0) ttb = 0;
    const u16* xrow0 = X + ((size_t)tta * 32 + ba) * 512 + quad * 8;
    const u16* xrow1 = X + ((size_t)ttb * 32 + bb) * 512 + quad * 8;
    bf16x8 ax0[16], ax1[16];
#pragma unroll
    for (int ks = 0; ks < 16; ++ks) {
      ax0[ks] = *(const bf16x8*)(xrow0 + (size_t)ks * 32);
      ax1[ks] = *(const bf16x8*)(xrow1 + (size_t)ks * 32);
    }

    // ---- wait: all blocks of my direction have published h(t) ----
    if (wid == 0) {
      for (;;) {
        unsigned v = __hip_atomic_load(pollflag, __ATOMIC_RELAXED, __HIP_MEMORY_SCOPE_AGENT);
        if (__all((int)(v >= (unsigned)t))) break;
        __builtin_amdgcn_s_sleep(1);
      }
    }
    __syncthreads();
    asm volatile("" ::: "memory");   // compiler-only barrier: no hoisting

    // ---- stage h(t): coalesced 8B LLC loads (lane-consecutive) ----
    u64 hstg[16];
#pragma unroll
    for (int j = 0; j < 16; ++j)
      hstg[j] = ld_dev64(hb + j * 1024 + tid * 4);

    // x-part MFMAs overlap the staging loads' LLC latency (no dependence)
    f32x4 a0x = {0.f,0.f,0.f,0.f}, a1x = {0.f,0.f,0.f,0.f};
#pragma unroll
    for (int ks = 0; ks < 16; ++ks) {
      a0x = __builtin_amdgcn_mfma_f32_16x16x32_bf16(ax0[ks], bxw[ks], a0x, 0, 0, 0);
      a1x = __builtin_amdgcn_mfma_f32_16x16x32_bf16(ax1[ks], bxw[ks], a1x, 0, 0, 0);
    }

    // write staged h into padded LDS image (2-way banks = free)
#pragma unroll
    for (int j = 0; j < 16; ++j) {
      int g = j * 1024 + tid * 4;                 // u16 element index
      *(u64*)&h_l[(g >> 9) * HROW + (g & 511)] = hstg[j];
    }
    __syncthreads();

    // ---- h-part MFMAs from LDS fragments ----
    f32x4 a0h = {0.f,0.f,0.f,0.f}, a1h = {0.f,0.f,0.f,0.f};
    const u16* hl0 = h_l + (size_t)l15 * HROW + quad * 8;
    const u16* hl1 = h_l + (size_t)(16 + l15) * HROW + quad * 8;
#pragma unroll
    for (int ks = 0; ks < 16; ++ks) {
      bf16x8 f0 = *(const bf16x8*)(hl0 + ks * 32);
      bf16x8 f1 = *(const bf16x8*)(hl1 + ks * 32);
      a0h = __builtin_amdgcn_mfma_f32_16x16x32_bf16(f0, bh[ks], a0h, 0, 0, 0);
      a1h = __builtin_amdgcn_mfma_f32_16x16x32_bf16(f1, bh[ks], a1h, 0, 0, 0);
    }
    f32x4 acc0 = a0x + a0h, acc1 = a1x + a1h;
    // C/D layout: row (=batch in tile) = quad*4+r, col (=gate col) = l15
#pragma unroll
    for (int r = 0; r < 4; ++r) {
      pre[wid][quad * 4 + r][l15]      = acc0[r];
      pre[wid][16 + quad * 4 + r][l15] = acc1[r];
    }
    __syncthreads();

    // ---- cell update ----
    int len0 = len_s[b0], len1 = len_s[b1];
    int tt0 = (dir == 0) ? t : (len0 - 1 - t);
    int tt1 = (dir == 0) ? t : (len1 - 1 - t);
    bool m0 = (dir == 0) ? (t < len0) : (tt0 >= 0);
    bool m1 = (dir == 0) ? (t < len1) : (tt1 >= 0);
    if (tt0 < 0) tt0 = 0;
    if (tt1 < 0) tt1 = 0;

    float hold0 = h_m[b0][colv], hold1 = h_m[b1][colv];
    float hn0 = 0.f, hn1 = 0.f;
    if (m0) {
      float gi = pre[0][b0][colv] + bi,  gf = pre[1][b0][colv] + bfv;
      float gg = pre[2][b0][colv] + bg,  go = pre[3][b0][colv] + bo;
      float cn = sigm(gf) * c_m[b0][colv] + sigm(gi) * tanh_s(gg);
      hn0 = sigm(go) * tanh_s(cn);
      c_m[b0][colv] = cn; h_m[b0][colv] = hn0; hold0 = hn0;
    }
    if (m1) {
      float gi = pre[0][b1][colv] + bi,  gf = pre[1][b1][colv] + bfv;
      float gg = pre[2][b1][colv] + bg,  go = pre[3][b1][colv] + bo;
      float cn = sigm(gf) * c_m[b1][colv] + sigm(gi) * tanh_s(gg);
      hn1 = sigm(go) * tanh_s(cn);
      c_m[b1][colv] = cn; h_m[b1][colv] = hn1; hold1 = hn1;
    }

    // ---- h(t+1) publish: shfl-pack pairs -> 4B LLC-direct stores ----
    unsigned p0 = (unsigned)f2bf(hold0), p1 = (unsigned)f2bf(hold1);
    unsigned q0 = (unsigned)__shfl_xor((int)p0, 1);
    unsigned q1 = (unsigned)__shfl_xor((int)p1, 1);
    if ((colv & 1) == 0) {
      st_dev32(hbw + (size_t)b0 * 512 + hcol, p0 | (q0 << 16));
      st_dev32(hbw + (size_t)b1 * 512 + hcol, p1 | (q1 << 16));
    }
    asm volatile("" ::: "memory");
    __syncthreads();   // vmcnt(0) drain: every wave's h stores acked at LLC
    if (tid == 0)
      __hip_atomic_store(myflag, (unsigned)(t + 1), __ATOMIC_RELAXED, __HIP_MEMORY_SCOPE_AGENT);

    // out accumulation fully off the critical path
    if (m0) atomicAdd(out + (size_t)(tt0 * 32 + b0) * 512 + hcol, hn0);
    if (m1) atomicAdd(out + (size_t)(tt1 * 32 + b1) * 512 + hcol, hn1);
  }

  // finals: h_n (2,B,H), c_n (2,B,H)
  out[HO + (size_t)dir * 16384 + (size_t)b0 * 512 + hcol] = h_m[b0][colv];
  out[HO + (size_t)dir * 16384 + (size_t)b1 * 512 + hcol] = h_m[b1][colv];
  out[CO + (size_t)dir * 16384 + (size_t)b0 * 512 + hcol] = c_m[b0][colv];
  out[CO + (size_t)dir * 16384 + (size_t)b1 * 512 + hcol] = c_m[b1][colv];
}

extern "C" void kernel_launch(void* const* d_in, const int* in_sizes, int n_in,
                              void* d_out, int out_size, void* d_ws, size_t ws_size,
                              hipStream_t stream) {
  const float* x     = (const float*)d_in[0];
  const int*   lens  = (const int*)d_in[1];
  const float* wih_f = (const float*)d_in[2];
  const float* whh_f = (const float*)d_in[3];
  const float* bih_f = (const float*)d_in[4];
  const float* bhh_f = (const float*)d_in[5];
  const float* wih_b = (const float*)d_in[6];
  const float* whh_b = (const float*)d_in[7];
  const float* bih_b = (const float*)d_in[8];
  const float* bhh_b = (const float*)d_in[9];
  float* out = (float*)d_out;
  char* ws = (char*)d_ws;

  u16*      xb   = (u16*)(ws + O_X);
  u16*      Wih  = (u16*)(ws + O_WIH);
  u16*      Whh  = (u16*)(ws + O_WHH);
  float*    bias = (float*)(ws + O_BIAS);
  u16*      hbuf = (u16*)(ws + O_HBUF);
  unsigned* flg  = (unsigned*)(ws + O_FLG);

  hipMemsetAsync(hbuf, 0, 131072 + 4096, stream);               // h dbl-buf + flags
  hipMemsetAsync(d_out, 0, (size_t)out_size * 4, stream);       // out accumulated via atomics

  cast_x_k<<<19200, 256, 0, stream>>>((const float4*)x, xb);
  prep_w_k<<<8192, 256, 0, stream>>>(wih_f, whh_f, bih_f, bhh_f,
                                     wih_b, whh_b, bih_b, bhh_b, Wih, Whh, bias);
  lstm_rec<<<64, 256, 0, stream>>>(xb, Wih, Whh, bias, lens, hbuf, out, flg);
}